// Round 4
// baseline (351.556 us; speedup 1.0000x reference)
//
#include <hip/hip_runtime.h>
#include <hip/hip_bf16.h>
#include <math.h>

constexpr int C = 1000;
constexpr int B = 65536;
constexpr int SP = 1024;         // padded bf16 S row stride (2 KB/row, 16B-aligned)
constexpr float SMOOTH = 0.1f;
constexpr int NBLK = B / 4;      // 4 waves per block, 1 sample per wave

typedef float f4 __attribute__((ext_vector_type(4)));
typedef short s8 __attribute__((ext_vector_type(8)));

__device__ inline float bf2f(short u) {
    unsigned v = ((unsigned)(unsigned short)u) << 16;
    return __builtin_bit_cast(float, v);
}

__device__ inline float wave_reduce_max(float v) {
    #pragma unroll
    for (int off = 32; off > 0; off >>= 1)
        v = fmaxf(v, __shfl_xor(v, off, 64));
    return v;
}
__device__ inline float wave_reduce_sum(float v) {
    #pragma unroll
    for (int off = 32; off > 0; off >>= 1)
        v += __shfl_xor(v, off, 64);
    return v;
}
__device__ inline float block_reduce_max(float v, float* sm) {
    v = wave_reduce_max(v);
    int wave = threadIdx.x >> 6, lane = threadIdx.x & 63;
    if (lane == 0) sm[wave] = v;
    __syncthreads();
    float r = fmaxf(fmaxf(sm[0], sm[1]), fmaxf(sm[2], sm[3]));
    __syncthreads();
    return r;
}
__device__ inline float block_reduce_sum(float v, float* sm) {
    v = wave_reduce_sum(v);
    int wave = threadIdx.x >> 6, lane = threadIdx.x & 63;
    if (lane == 0) sm[wave] = v;
    __syncthreads();
    float r = sm[0] + sm[1] + sm[2] + sm[3];
    __syncthreads();
    return r;
}

// Kernel 1: per class row t: A = softmax(row); S[t,j] = 0.1*(1-A_j)/(1-A_tt),
// S[t,t] = 0.9, stored bf16 with row stride SP (cols C..SP-1 zeroed);
// Srow[t] = sum_j S[t,j] in f32.
__global__ __launch_bounds__(256) void smooth_kernel(
        const float* __restrict__ ca, __hip_bfloat16* __restrict__ S,
        float* __restrict__ Srow) {
    __shared__ float sm[4];
    __shared__ float diag_sh;
    int t = blockIdx.x;
    int tid = threadIdx.x;
    const float* row = ca + (size_t)t * C;

    float v[4];
    float m = -INFINITY;
    #pragma unroll
    for (int k = 0; k < 4; k++) {
        int j = tid + k * 256;
        v[k] = (j < C) ? row[j] : -INFINITY;
        m = fmaxf(m, v[k]);
    }
    m = block_reduce_max(m, sm);

    float a[4];
    float zl = 0.f;
    #pragma unroll
    for (int k = 0; k < 4; k++) {
        int j = tid + k * 256;
        a[k] = (j < C) ? __expf(v[k] - m) : 0.f;
        zl += a[k];
    }
    float z = block_reduce_sum(zl, sm);
    float inv_z = 1.0f / z;

    float sumA_l = 0.f;
    #pragma unroll
    for (int k = 0; k < 4; k++) {
        a[k] *= inv_z;
        sumA_l += a[k];
        int j = tid + k * 256;
        if (j == t) diag_sh = a[k];   // visible after syncthreads inside next reduce
    }
    float sumA = block_reduce_sum(sumA_l, sm);

    float sums = sumA - diag_sh;
    float coef = SMOOTH / sums;
    __hip_bfloat16* Srt = S + (size_t)t * SP;
    float srow_l = 0.f;
    #pragma unroll
    for (int k = 0; k < 4; k++) {
        int j = tid + k * 256;      // covers 0..1023 exactly
        float s = 0.f;
        if (j < C) {
            s = (j == t) ? (1.0f - SMOOTH) : (1.0f - a[k]) * coef;
            srow_l += s;
        }
        Srt[j] = __float2bfloat16(s);   // pad cols get 0
    }
    float srow = block_reduce_sum(srow_l, sm);
    if (tid == 0) Srow[t] = srow;
}

// Kernel 2: one wave per sample. Safe unshifted logsumexp (x ~ N(0,1)).
// loss_b = log(sum_j exp(x_bj)) * Srow[t] - dot(S[t,:], x[b,:])
// Per lane: chunks c0=lane, c1=lane+64 of 8 columns each (1024 cols incl. pad).
// S: 2x bf16x8 loads; x: 4x float4 non-temporal loads.
__global__ __launch_bounds__(256) void loss_kernel(
        const float* __restrict__ x, const short* __restrict__ S,
        const float* __restrict__ Srow, const int* __restrict__ tgt,
        float* __restrict__ partials) {
    int wave = threadIdx.x >> 6, lane = threadIdx.x & 63;
    int b = blockIdx.x * 4 + wave;          // B == 4*gridDim.x exactly

    int t = tgt[b];
    float ss = Srow[t];
    const f4* xr = (const f4*)(x + (size_t)b * C);
    const s8* sr = (const s8*)(S + (size_t)t * SP);

    int c0 = lane, c1 = lane + 64;
    bool ok = (c1 <= 124);                  // chunk 124 = cols 992..999 (last valid x)

    s8 sv0 = sr[c0];
    s8 sv1 = sr[c1];                        // pad chunks are zeros, always in-bounds
    f4 xa = __builtin_nontemporal_load(xr + 2 * c0);
    f4 xb = __builtin_nontemporal_load(xr + 2 * c0 + 1);
    f4 xc = f4{0.f, 0.f, 0.f, 0.f};
    f4 xd = f4{0.f, 0.f, 0.f, 0.f};
    if (ok) {
        xc = __builtin_nontemporal_load(xr + 2 * c1);
        xd = __builtin_nontemporal_load(xr + 2 * c1 + 1);
    }

    float zl = 0.f, dl = 0.f;
    zl += (__expf(xa.x) + __expf(xa.y)) + (__expf(xa.z) + __expf(xa.w));
    zl += (__expf(xb.x) + __expf(xb.y)) + (__expf(xb.z) + __expf(xb.w));
    zl += (__expf(xc.x) + __expf(xc.y)) + (__expf(xc.z) + __expf(xc.w));
    zl += (__expf(xd.x) + __expf(xd.y)) + (__expf(xd.z) + __expf(xd.w));
    if (!ok) zl -= 8.0f;                    // remove exp(0)=1 pad terms

    dl = fmaf(bf2f(sv0[0]), xa.x, dl);
    dl = fmaf(bf2f(sv0[1]), xa.y, dl);
    dl = fmaf(bf2f(sv0[2]), xa.z, dl);
    dl = fmaf(bf2f(sv0[3]), xa.w, dl);
    dl = fmaf(bf2f(sv0[4]), xb.x, dl);
    dl = fmaf(bf2f(sv0[5]), xb.y, dl);
    dl = fmaf(bf2f(sv0[6]), xb.z, dl);
    dl = fmaf(bf2f(sv0[7]), xb.w, dl);
    dl = fmaf(bf2f(sv1[0]), xc.x, dl);
    dl = fmaf(bf2f(sv1[1]), xc.y, dl);
    dl = fmaf(bf2f(sv1[2]), xc.z, dl);
    dl = fmaf(bf2f(sv1[3]), xc.w, dl);
    dl = fmaf(bf2f(sv1[4]), xd.x, dl);
    dl = fmaf(bf2f(sv1[5]), xd.y, dl);
    dl = fmaf(bf2f(sv1[6]), xd.z, dl);
    dl = fmaf(bf2f(sv1[7]), xd.w, dl);

    // fused dual reduction: one 6-round shfl pass for (Z, d)
    #pragma unroll
    for (int off = 32; off > 0; off >>= 1) {
        zl += __shfl_xor(zl, off, 64);
        dl += __shfl_xor(dl, off, 64);
    }

    if (lane == 0)
        partials[b] = __logf(zl) * ss - dl;
}

// Kernel 3: sum B partials -> out = sum / B. Single 1024-thread block.
__global__ __launch_bounds__(1024) void reduce_kernel(
        const float* __restrict__ partials, float* __restrict__ out) {
    __shared__ float sm[16];
    const f4* p4 = (const f4*)partials;      // B/4 = 16384 f4 = 1024 threads * 16
    float s = 0.f;
    #pragma unroll
    for (int k = 0; k < 16; k++) {
        f4 v = p4[threadIdx.x + k * 1024];
        s += (v.x + v.y) + (v.z + v.w);
    }
    s = wave_reduce_sum(s);
    int wave = threadIdx.x >> 6, lane = threadIdx.x & 63;
    if (lane == 0) sm[wave] = s;
    __syncthreads();
    if (threadIdx.x == 0) {
        float tot = 0.f;
        #pragma unroll
        for (int w = 0; w < 16; w++) tot += sm[w];
        out[0] = tot * (1.0f / (float)B);
    }
}

extern "C" void kernel_launch(void* const* d_in, const int* in_sizes, int n_in,
                              void* d_out, int out_size, void* d_ws, size_t ws_size,
                              hipStream_t stream) {
    const float* x   = (const float*)d_in[0];
    const float* ca  = (const float*)d_in[1];
    const int*   tgt = (const int*)d_in[2];
    float* out = (float*)d_out;

    __hip_bfloat16* S = (__hip_bfloat16*)d_ws;        // C*SP bf16 = 2 MB
    float* Srow       = (float*)(S + (size_t)C * SP); // C floats
    float* partials   = Srow + C;                     // B floats = 256 KB

    smooth_kernel<<<C, 256, 0, stream>>>(ca, S, Srow);
    loss_kernel<<<NBLK, 256, 0, stream>>>(x, (const short*)S, Srow, tgt, partials);
    reduce_kernel<<<1, 1024, 0, stream>>>(partials, out);
}